// Round 2
// baseline (464.491 us; speedup 1.0000x reference)
//
#include <hip/hip_runtime.h>
#include <hip/hip_bf16.h>

// g[b,h,w] = (1/N) * sum_n conj(H[n]) * (H[n]*x[b] - y[b,n])
//          = x[b]*(1/N)*sum_n |H[n]|^2  -  (1/N)*sum_n conj(H[n])*y[b,n]
//
// Round 2: n-reduction split SPLIT ways across blockIdx.y to raise occupancy
// from 2 blocks/CU (8 waves/CU) to 8 blocks/CU (32 waves/CU). Partial results
// accumulated with fp32 atomicAdd into d_out (zeroed via async memset on the
// stream first). Linear in the partials, so x*s0_partial contributions sum
// correctly across segments.

constexpr int SPLIT = 4;

__global__ void __launch_bounds__(256) idt_partial_kernel(
    const float4* __restrict__ H4,   // [N][P]
    const float4* __restrict__ Y4,   // [B=2][N][P]
    const float4* __restrict__ X4,   // [B=2][P]
    float* __restrict__ O,           // [B=2][P][4] floats (atomic accumulate)
    const int* __restrict__ nbf,
    int N, int P, int nseg)
{
    int p = blockIdx.x * blockDim.x + threadIdx.x;
    if (p >= P) return;

    int n0 = blockIdx.y * nseg;
    int n1 = min(N, n0 + nseg);

    float s0 = 0.f, s1 = 0.f;
    float a00r = 0.f, a00i = 0.f, a01r = 0.f, a01i = 0.f;  // b=0
    float a10r = 0.f, a10i = 0.f, a11r = 0.f, a11i = 0.f;  // b=1

    const float4* hp = H4 + (size_t)n0 * P + p;
    const float4* y0 = Y4 + (size_t)n0 * P + p;                     // b=0
    const float4* y1 = Y4 + ((size_t)N + n0) * P + p;               // b=1

    #pragma unroll 4
    for (int n = n0; n < n1; ++n) {
        float4 hv = *hp; hp += P;
        float4 v0 = *y0; y0 += P;
        float4 v1 = *y1; y1 += P;

        s0 += hv.x * hv.x + hv.y * hv.y;
        s1 += hv.z * hv.z + hv.w * hv.w;

        // conj(H)*y = (Hr*yr + Hi*yi) + i(Hr*yi - Hi*yr)
        a00r += hv.x * v0.x + hv.y * v0.y;
        a00i += hv.x * v0.y - hv.y * v0.x;
        a01r += hv.z * v0.z + hv.w * v0.w;
        a01i += hv.z * v0.w - hv.w * v0.z;

        a10r += hv.x * v1.x + hv.y * v1.y;
        a10i += hv.x * v1.y - hv.y * v1.x;
        a11r += hv.z * v1.z + hv.w * v1.w;
        a11i += hv.z * v1.w - hv.w * v1.z;
    }

    float inv = 1.0f / (float)nbf[0];

    float4 x0 = X4[p];
    float4 x1 = X4[(size_t)P + p];

    float* ob0 = O + (size_t)p * 4;
    float* ob1 = O + ((size_t)P + p) * 4;

    atomicAdd(ob0 + 0, (x0.x * s0 - a00r) * inv);
    atomicAdd(ob0 + 1, (x0.y * s0 - a00i) * inv);
    atomicAdd(ob0 + 2, (x0.z * s1 - a01r) * inv);
    atomicAdd(ob0 + 3, (x0.w * s1 - a01i) * inv);

    atomicAdd(ob1 + 0, (x1.x * s0 - a10r) * inv);
    atomicAdd(ob1 + 1, (x1.y * s0 - a10i) * inv);
    atomicAdd(ob1 + 2, (x1.z * s1 - a11r) * inv);
    atomicAdd(ob1 + 3, (x1.w * s1 - a11i) * inv);
}

extern "C" void kernel_launch(void* const* d_in, const int* in_sizes, int n_in,
                              void* d_out, int out_size, void* d_ws, size_t ws_size,
                              hipStream_t stream) {
    const float* f_ipt = (const float*)d_in[0];   // [B,H,W,2]
    const float* f_y   = (const float*)d_in[1];   // [B,N,H,W,2]
    const float* Hreal = (const float*)d_in[2];   // [N,H,W,2]
    const int*   nbf   = (const int*)d_in[3];     // scalar NBFkeep

    const int B = in_sizes[1] / in_sizes[2];      // = 2
    const int N = in_sizes[1] / in_sizes[0];      // = 64
    const int P = in_sizes[0] / B / 4;            // = 131072 float4 groups per batch
    const int nseg = (N + SPLIT - 1) / SPLIT;

    // d_out is poisoned 0xAA before every launch; zero it (memset node is
    // graph-capture safe).
    hipMemsetAsync(d_out, 0, (size_t)out_size * sizeof(float), stream);

    dim3 block(256);
    dim3 grid((P + block.x - 1) / block.x, SPLIT);
    idt_partial_kernel<<<grid, block, 0, stream>>>(
        (const float4*)Hreal, (const float4*)f_y, (const float4*)f_ipt,
        (float*)d_out, nbf, N, P, nseg);
}

// Round 3
// 437.125 us; speedup vs baseline: 1.0626x; 1.0626x over previous
//
#include <hip/hip_runtime.h>
#include <hip/hip_bf16.h>

// g[b,h,w] = (1/N) * sum_n conj(H[n]) * (H[n]*x[b] - y[b,n])
//          = x[b]*(1/N)*sum_n |H[n]|^2  -  (1/N)*sum_n conj(H[n])*y[b,n]
//
// Round 3: occupancy experiment WITHOUT atomics. blockDim=(256,4): tid.y
// splits the n-range 4 ways (16 frames each), per-thread partials (10 floats)
// reduced via LDS, tid.y==0 applies the epilogue and stores. One dispatch,
// zero extra HBM traffic vs round 1, 16 waves/CU resident (vs 8).
// __launch_bounds__(1024) caps VGPR at 128 so the 16-wave block fits a CU.

typedef float f4 __attribute__((ext_vector_type(4)));

__global__ void __launch_bounds__(1024) idt_fused_kernel(
    const f4* __restrict__ H4,   // [N][P]
    const f4* __restrict__ Y4,   // [B=2][N][P]
    const f4* __restrict__ X4,   // [B=2][P]
    f4* __restrict__ O4,         // [B=2][P]
    const int* __restrict__ nbf,
    int N, int P)
{
    // [ty][tx][10] partials. lane stride 10 floats -> 2-way bank aliasing (free).
    __shared__ float red[4][256][10];

    const int tx = threadIdx.x;          // 0..255 -> p lane
    const int ty = threadIdx.y;          // 0..3   -> n segment
    const int p  = blockIdx.x * 256 + tx;

    const int nseg = N >> 2;             // 16
    const int n0   = ty * nseg;

    // acc: s0, s1, a00r, a00i, a01r, a01i, a10r, a10i, a11r, a11i
    float acc[10];
    #pragma unroll
    for (int j = 0; j < 10; ++j) acc[j] = 0.f;

    if (p < P) {
        const f4* hp = H4 + (size_t)n0 * P + p;
        const f4* y0 = Y4 + (size_t)n0 * P + p;               // b=0
        const f4* y1 = Y4 + ((size_t)N + n0) * P + p;         // b=1

        #pragma unroll 4
        for (int n = 0; n < nseg; ++n) {
            f4 hv = *hp; hp += P;
            f4 v0 = *y0; y0 += P;
            f4 v1 = *y1; y1 += P;

            acc[0] += hv.x * hv.x + hv.y * hv.y;              // |H|^2 pix0
            acc[1] += hv.z * hv.z + hv.w * hv.w;              // |H|^2 pix1

            // conj(H)*y = (Hr*yr + Hi*yi) + i(Hr*yi - Hi*yr)
            acc[2] += hv.x * v0.x + hv.y * v0.y;
            acc[3] += hv.x * v0.y - hv.y * v0.x;
            acc[4] += hv.z * v0.z + hv.w * v0.w;
            acc[5] += hv.z * v0.w - hv.w * v0.z;

            acc[6] += hv.x * v1.x + hv.y * v1.y;
            acc[7] += hv.x * v1.y - hv.y * v1.x;
            acc[8] += hv.z * v1.z + hv.w * v1.w;
            acc[9] += hv.z * v1.w - hv.w * v1.z;
        }
    }

    #pragma unroll
    for (int j = 0; j < 10; ++j) red[ty][tx][j] = acc[j];
    __syncthreads();

    if (ty == 0 && p < P) {
        float r[10];
        #pragma unroll
        for (int j = 0; j < 10; ++j)
            r[j] = red[0][tx][j] + red[1][tx][j] + red[2][tx][j] + red[3][tx][j];

        const float inv = 1.0f / (float)nbf[0];
        f4 x0 = X4[p];
        f4 x1 = X4[(size_t)P + p];

        f4 o0, o1;
        o0.x = (x0.x * r[0] - r[2]) * inv;
        o0.y = (x0.y * r[0] - r[3]) * inv;
        o0.z = (x0.z * r[1] - r[4]) * inv;
        o0.w = (x0.w * r[1] - r[5]) * inv;

        o1.x = (x1.x * r[0] - r[6]) * inv;
        o1.y = (x1.y * r[0] - r[7]) * inv;
        o1.z = (x1.z * r[1] - r[8]) * inv;
        o1.w = (x1.w * r[1] - r[9]) * inv;

        O4[p] = o0;
        O4[(size_t)P + p] = o1;
    }
}

extern "C" void kernel_launch(void* const* d_in, const int* in_sizes, int n_in,
                              void* d_out, int out_size, void* d_ws, size_t ws_size,
                              hipStream_t stream) {
    const float* f_ipt = (const float*)d_in[0];   // [B,H,W,2]
    const float* f_y   = (const float*)d_in[1];   // [B,N,H,W,2]
    const float* Hreal = (const float*)d_in[2];   // [N,H,W,2]
    const int*   nbf   = (const int*)d_in[3];     // scalar NBFkeep

    const int B = in_sizes[1] / in_sizes[2];      // = 2
    const int N = in_sizes[1] / in_sizes[0];      // = 64
    const int P = in_sizes[0] / B / 4;            // = 131072 float4 groups per batch

    dim3 block(256, 4);
    dim3 grid((P + 255) / 256);
    idt_fused_kernel<<<grid, block, 0, stream>>>(
        (const f4*)Hreal, (const f4*)f_y, (const f4*)f_ipt,
        (f4*)d_out, nbf, N, P);
}

// Round 4
// 411.387 us; speedup vs baseline: 1.1291x; 1.0626x over previous
//
#include <hip/hip_runtime.h>
#include <hip/hip_bf16.h>

// g[b,h,w] = (1/N) * sum_n conj(H[n]) * (H[n]*x[b] - y[b,n])
//          = x[b]*(1/N)*sum_n |H[n]|^2  -  (1/N)*sum_n conj(H[n])*y[b,n]
//
// Round 4: identical structure to round 1 (best so far: 512 blocks x 256,
// one float4-group per thread, stream over n) but ALL streaming accesses are
// nontemporal (`nt` cache hint): the 406 MB of read-once data should not
// allocate/churn L2. Occupancy was proven a non-factor in R3; this tests the
// L2/DRAM read path at constant bytes and constant instruction mix.

typedef float f4 __attribute__((ext_vector_type(4)));

__global__ void __launch_bounds__(256) idt_fused_kernel(
    const f4* __restrict__ H4,   // [N][P]
    const f4* __restrict__ Y4,   // [B=2][N][P]
    const f4* __restrict__ X4,   // [B=2][P]
    f4* __restrict__ O4,         // [B=2][P]
    const int* __restrict__ nbf,
    int N, int P)
{
    int p = blockIdx.x * blockDim.x + threadIdx.x;
    if (p >= P) return;

    float s0 = 0.f, s1 = 0.f;
    float a00r = 0.f, a00i = 0.f, a01r = 0.f, a01i = 0.f;  // b=0
    float a10r = 0.f, a10i = 0.f, a11r = 0.f, a11i = 0.f;  // b=1

    const f4* hp = H4 + p;
    const f4* y0 = Y4 + p;                       // b=0
    const f4* y1 = Y4 + (size_t)N * P + p;       // b=1

    #pragma unroll 4
    for (int n = 0; n < N; ++n) {
        f4 hv = __builtin_nontemporal_load(hp + (size_t)n * P);
        f4 v0 = __builtin_nontemporal_load(y0 + (size_t)n * P);
        f4 v1 = __builtin_nontemporal_load(y1 + (size_t)n * P);

        s0 += hv.x * hv.x + hv.y * hv.y;
        s1 += hv.z * hv.z + hv.w * hv.w;

        // conj(H)*y = (Hr*yr + Hi*yi) + i(Hr*yi - Hi*yr)
        a00r += hv.x * v0.x + hv.y * v0.y;
        a00i += hv.x * v0.y - hv.y * v0.x;
        a01r += hv.z * v0.z + hv.w * v0.w;
        a01i += hv.z * v0.w - hv.w * v0.z;

        a10r += hv.x * v1.x + hv.y * v1.y;
        a10i += hv.x * v1.y - hv.y * v1.x;
        a11r += hv.z * v1.z + hv.w * v1.w;
        a11i += hv.z * v1.w - hv.w * v1.z;
    }

    float inv = 1.0f / (float)nbf[0];

    f4 x0 = X4[p];
    f4 x1 = X4[(size_t)P + p];

    f4 o0, o1;
    o0.x = (x0.x * s0 - a00r) * inv;
    o0.y = (x0.y * s0 - a00i) * inv;
    o0.z = (x0.z * s1 - a01r) * inv;
    o0.w = (x0.w * s1 - a01i) * inv;

    o1.x = (x1.x * s0 - a10r) * inv;
    o1.y = (x1.y * s0 - a10i) * inv;
    o1.z = (x1.z * s1 - a11r) * inv;
    o1.w = (x1.w * s1 - a11i) * inv;

    __builtin_nontemporal_store(o0, O4 + p);
    __builtin_nontemporal_store(o1, O4 + (size_t)P + p);
}

extern "C" void kernel_launch(void* const* d_in, const int* in_sizes, int n_in,
                              void* d_out, int out_size, void* d_ws, size_t ws_size,
                              hipStream_t stream) {
    const float* f_ipt = (const float*)d_in[0];   // [B,H,W,2]
    const float* f_y   = (const float*)d_in[1];   // [B,N,H,W,2]
    const float* Hreal = (const float*)d_in[2];   // [N,H,W,2]
    const int*   nbf   = (const int*)d_in[3];     // scalar NBFkeep

    const int B = in_sizes[1] / in_sizes[2];      // = 2
    const int N = in_sizes[1] / in_sizes[0];      // = 64
    const int P = in_sizes[0] / B / 4;            // = 131072 float4 groups per batch

    dim3 block(256);
    dim3 grid((P + block.x - 1) / block.x);
    idt_fused_kernel<<<grid, block, 0, stream>>>(
        (const f4*)Hreal, (const f4*)f_y, (const f4*)f_ipt,
        (f4*)d_out, nbf, N, P);
}

// Round 5
// 405.338 us; speedup vs baseline: 1.1459x; 1.0149x over previous
//
#include <hip/hip_runtime.h>
#include <hip/hip_bf16.h>

// g[b,h,w] = (1/N) * sum_n conj(H[n]) * (H[n]*x[b] - y[b,n])
//          = x[b]*(1/N)*sum_n |H[n]|^2  -  (1/N)*sum_n conj(H[n])*y[b,n]
//
// Round 5: R4 (NT loads/stores, 512x256, 1 float4-group/thread) + manual
// software pipeline: the 12 NT loads for n-group g+1 are issued BEFORE the
// FMAs of group g, so ~12KB/wave stays in flight during compute instead of
// only during a waitcnt stall. Same bytes, same occupancy; tests whether the
// waitcnt duty cycle (vs a structural read-path ceiling) limits delivered BW.

typedef float f4 __attribute__((ext_vector_type(4)));

#define ACCUM(hv, v0, v1)                                   \
    do {                                                    \
        s0 += (hv).x * (hv).x + (hv).y * (hv).y;            \
        s1 += (hv).z * (hv).z + (hv).w * (hv).w;            \
        a00r += (hv).x * (v0).x + (hv).y * (v0).y;          \
        a00i += (hv).x * (v0).y - (hv).y * (v0).x;          \
        a01r += (hv).z * (v0).z + (hv).w * (v0).w;          \
        a01i += (hv).z * (v0).w - (hv).w * (v0).z;          \
        a10r += (hv).x * (v1).x + (hv).y * (v1).y;          \
        a10i += (hv).x * (v1).y - (hv).y * (v1).x;          \
        a11r += (hv).z * (v1).z + (hv).w * (v1).w;          \
        a11i += (hv).z * (v1).w - (hv).w * (v1).z;          \
    } while (0)

__global__ void __launch_bounds__(256) idt_fused_kernel(
    const f4* __restrict__ H4,   // [N][P]
    const f4* __restrict__ Y4,   // [B=2][N][P]
    const f4* __restrict__ X4,   // [B=2][P]
    f4* __restrict__ O4,         // [B=2][P]
    const int* __restrict__ nbf,
    int N, int P)
{
    int p = blockIdx.x * blockDim.x + threadIdx.x;
    if (p >= P) return;

    float s0 = 0.f, s1 = 0.f;
    float a00r = 0.f, a00i = 0.f, a01r = 0.f, a01i = 0.f;  // b=0
    float a10r = 0.f, a10i = 0.f, a11r = 0.f, a11i = 0.f;  // b=1

    const f4* hp = H4 + p;
    const f4* y0 = Y4 + p;                       // b=0
    const f4* y1 = Y4 + (size_t)N * P + p;       // b=1

    const int G = N >> 2;                        // groups of 4 n's

    f4 cH[4], c0[4], c1[4];
    #pragma unroll
    for (int j = 0; j < 4; ++j) {
        cH[j] = __builtin_nontemporal_load(hp + (size_t)j * P);
        c0[j] = __builtin_nontemporal_load(y0 + (size_t)j * P);
        c1[j] = __builtin_nontemporal_load(y1 + (size_t)j * P);
    }

    for (int g = 0; g < G - 1; ++g) {
        const size_t base = (size_t)(g + 1) * 4 * P;

        // issue next group's loads first (stay outstanding through compute)
        f4 nH[4], n0[4], n1[4];
        #pragma unroll
        for (int j = 0; j < 4; ++j) {
            nH[j] = __builtin_nontemporal_load(hp + base + (size_t)j * P);
            n0[j] = __builtin_nontemporal_load(y0 + base + (size_t)j * P);
            n1[j] = __builtin_nontemporal_load(y1 + base + (size_t)j * P);
        }

        #pragma unroll
        for (int j = 0; j < 4; ++j) ACCUM(cH[j], c0[j], c1[j]);

        #pragma unroll
        for (int j = 0; j < 4; ++j) { cH[j] = nH[j]; c0[j] = n0[j]; c1[j] = n1[j]; }
    }

    #pragma unroll
    for (int j = 0; j < 4; ++j) ACCUM(cH[j], c0[j], c1[j]);

    float inv = 1.0f / (float)nbf[0];

    f4 x0 = X4[p];
    f4 x1 = X4[(size_t)P + p];

    f4 o0, o1;
    o0.x = (x0.x * s0 - a00r) * inv;
    o0.y = (x0.y * s0 - a00i) * inv;
    o0.z = (x0.z * s1 - a01r) * inv;
    o0.w = (x0.w * s1 - a01i) * inv;

    o1.x = (x1.x * s0 - a10r) * inv;
    o1.y = (x1.y * s0 - a10i) * inv;
    o1.z = (x1.z * s1 - a11r) * inv;
    o1.w = (x1.w * s1 - a11i) * inv;

    __builtin_nontemporal_store(o0, O4 + p);
    __builtin_nontemporal_store(o1, O4 + (size_t)P + p);
}

extern "C" void kernel_launch(void* const* d_in, const int* in_sizes, int n_in,
                              void* d_out, int out_size, void* d_ws, size_t ws_size,
                              hipStream_t stream) {
    const float* f_ipt = (const float*)d_in[0];   // [B,H,W,2]
    const float* f_y   = (const float*)d_in[1];   // [B,N,H,W,2]
    const float* Hreal = (const float*)d_in[2];   // [N,H,W,2]
    const int*   nbf   = (const int*)d_in[3];     // scalar NBFkeep

    const int B = in_sizes[1] / in_sizes[2];      // = 2
    const int N = in_sizes[1] / in_sizes[0];      // = 64
    const int P = in_sizes[0] / B / 4;            // = 131072 float4 groups per batch

    dim3 block(256);
    dim3 grid((P + block.x - 1) / block.x);
    idt_fused_kernel<<<grid, block, 0, stream>>>(
        (const f4*)Hreal, (const f4*)f_y, (const f4*)f_ipt,
        (f4*)d_out, nbf, N, P);
}